// Round 9
// baseline (76615.112 us; speedup 1.0000x reference)
//
#include <hip/hip_runtime.h>
#include <math.h>

#define B_ 64
#define T_ 600
#define U_ 64
#define V_ 80
#define H_ 512
#define KA_ 10
#define KO_ 20

#define RW0   300      // u32 per padded L0 row   (600 f16)
#define RW12  556      // u32 per padded L1/2 row (1112 f16)
#define WOFF1 614400   // wpad32 u32-offset of L1 rows (2048*RW0)
#define WOFF2 1753088  // + 2048*RW12
#define WOFFW 2891776  // + 2048*RW12  (winW, 30 rows x 256 u32)
#define FSTRIDE 16     // u32 per flag slot (64B line)

typedef unsigned u32x4 __attribute__((ext_vector_type(4)));
typedef _Float16 h2_t __attribute__((ext_vector_type(2)));

__device__ __forceinline__ float sigmf(float x){ return 1.0f/(1.0f+expf(-x)); }

static __device__ __forceinline__ h2_t bch(unsigned u){ return __builtin_bit_cast(h2_t, u); }
static __device__ __forceinline__ unsigned pkh(float a, float b){
    return __builtin_bit_cast(unsigned, __builtin_amdgcn_cvt_pkrtz(a, b));
}
static __device__ __forceinline__ float hlo(unsigned u){ return (float)bch(u)[0]; }
static __device__ __forceinline__ float hhi(unsigned u){ return (float)bch(u)[1]; }

#if __has_builtin(__builtin_amdgcn_fdot2)
static __device__ __forceinline__ float fd2(unsigned a, unsigned b, float c){
    return __builtin_amdgcn_fdot2(bch(a), bch(b), c, false);
}
#else
static __device__ __forceinline__ float fd2(unsigned a, unsigned b, float c){
    return c + hlo(a)*hlo(b) + hhi(a)*hhi(b);
}
#endif

static __device__ __forceinline__ float dot8(uint4 q, uint4 w, float acc){
    acc = fd2(q.x, w.x, acc);
    acc = fd2(q.y, w.y, acc);
    acc = fd2(q.z, w.z, acc);
    acc = fd2(q.w, w.w, acc);
    return acc;
}

// --- coherent (MALL write-through / bypassing) primitives ---
static __device__ __forceinline__ unsigned coh_load_u32(const unsigned* p){
    unsigned v;
    asm volatile("global_load_dword %0, %1, off sc0 sc1\n\ts_waitcnt vmcnt(0)"
                 : "=v"(v) : "v"(p) : "memory");
    return v;
}
static __device__ __forceinline__ void coh_store_u32(unsigned* p, unsigned v){
    asm volatile("global_store_dword %0, %1, off sc0 sc1" :: "v"(p), "v"(v) : "memory");
}
static __device__ __forceinline__ void coh_store_u128(unsigned* p, u32x4 v){
    asm volatile("global_store_dwordx4 %0, %1, off sc0 sc1" :: "v"(p), "v"(v) : "memory");
}
// 64 per-block flags: lane i polls flag i; barrier afterwards.
static __device__ __forceinline__ void wait_role(const unsigned* f){
    if (threadIdx.x < 64){
        const unsigned* p = f + threadIdx.x*FSTRIDE;
        while (coh_load_u32(p) == 0){}
    }
    __syncthreads();
}

// ---------------------------------------------------------------------------
// Weight repack to f16 pairs, 16B-aligned sections:
// f16 idx: [0..2]=stroke, [3..7]=0, [8..87]=attn, [88..599]=own(L0)/cross(L1,2),
//          [600..1111]=own (L1/2 only)
__global__ __launch_bounds__(64) void k_prep(
    const float* __restrict__ W0ih, const float* __restrict__ W0hh,
    const float* __restrict__ W1ih, const float* __restrict__ W1hh,
    const float* __restrict__ W2ih, const float* __restrict__ W2hh,
    const float* __restrict__ winW,
    unsigned* __restrict__ wpad32)
{
    int r = blockIdx.x; int tid = threadIdx.x;
    if (r < 6144){
        int layer = r >> 11;
        int row = r & 2047;
        const float* ih; const float* hh; unsigned* dst; int RW;
        if (layer == 0){ ih = W0ih + (size_t)row*83;  hh = W0hh + (size_t)row*512; dst = wpad32 + (size_t)row*RW0;           RW = RW0; }
        else if (layer == 1){ ih = W1ih + (size_t)row*595; hh = W1hh + (size_t)row*512; dst = wpad32 + WOFF1 + (size_t)row*RW12; RW = RW12; }
        else { ih = W2ih + (size_t)row*595; hh = W2hh + (size_t)row*512; dst = wpad32 + WOFF2 + (size_t)row*RW12; RW = RW12; }
        for (int j = tid; j < RW; j += 64){
            float f[2];
            #pragma unroll
            for (int q = 0; q < 2; ++q){
                int e = 2*j + q;
                float v = 0.f;
                if (e < 3) v = ih[e];
                else if (e >= 8 && e < 88) v = ih[3 + e - 8];
                else if (e >= 88 && e < 600) v = (layer == 0) ? hh[e-88] : ih[83 + e - 88];
                else if (e >= 600 && e < 1112 && layer != 0) v = hh[e-600];
                f[q] = v;
            }
            dst[j] = pkh(f[0], f[1]);
        }
    } else {
        int rr = r - 6144;   // 0..29
        unsigned* dst = wpad32 + WOFFW + (size_t)rr*256;
        const float* src = winW + (size_t)rr*512;
        for (int j = tid; j < 256; j += 64)
            dst[j] = pkh(src[2*j], src[2*j+1]);
    }
}

// ---------------------------------------------------------------------------
// Persistent pipelined kernel. Grid 256 x 512:
//   bid [0,64)=L0 (8 units), [64,128)=L1, [128,192)=L2, [192,256)=window (batch wb).
// Weights live in LDS (staged once, f16 pairs). h/attn exchanged via MALL
// (sc0sc1 write-through, f16 pairs, uint4 packets [t][kp][b]).
// Flags: one 64B slot per producer block per t; plain stores; wave-parallel polls.
__global__ __launch_bounds__(512, 2) void k_pipe(
    const float* __restrict__ strokes,
    const int*   __restrict__ char_seq,
    const float* __restrict__ char_mask,
    const unsigned* __restrict__ wpad32,
    const float* __restrict__ winb,
    const float* __restrict__ b0, const float* __restrict__ b1, const float* __restrict__ b2,
    unsigned* __restrict__ out0b, unsigned* __restrict__ out1b, unsigned* __restrict__ out2b,
    unsigned* __restrict__ attnb, unsigned* __restrict__ flags)
{
    __builtin_amdgcn_fence(__ATOMIC_ACQUIRE, "agent");   // wipe stale L2 once per call

    unsigned* cf0 = flags;
    unsigned* cf1 = flags + 614400;
    unsigned* cf2 = flags + 1228800;
    unsigned* cfw = flags + 1843200;

    const int bid = blockIdx.x;
    const int tid = threadIdx.x;
    const int b   = tid & 63;
    const int r   = tid >> 6;   // wave id 0..7

    extern __shared__ unsigned dynls[];
    __shared__ float pp[30][16];
    __shared__ float sa[KA_], sbv[KA_], sk[KA_], skst[KA_];
    __shared__ float sphi[U_];
    __shared__ float satt[V_];
    __shared__ int   sseq[U_];
    __shared__ float smask[U_];

    if (bid >= 192){
        // ---------------- window role ----------------
        const int wb = bid - 192;
        unsigned* wlw = dynls;              // 7680 u32
        unsigned* shh = dynls + 7680;       // 256 u32 (512 f16 of h0)
        for (int i = tid; i < 7680; i += 512) wlw[i] = wpad32[WOFFW + i];
        if (tid < U_){ sseq[tid] = char_seq[wb*U_+tid]; smask[tid] = char_mask[wb*U_+tid]; }
        __syncthreads();
        for (int t = 0; t < T_; ++t){
            wait_role(cf0 + (size_t)t*1024);
            if (tid < 64)
                ((uint4*)shh)[tid] = ((const uint4*)out0b)[((size_t)t*64 + tid)*64 + wb];
            __syncthreads();
            if (tid < 480){
                int rr = tid >> 4, p = tid & 15;
                const unsigned* wr = wlw + rr*256;
                float acc = 0.f;
                #pragma unroll
                for (int i = 0; i < 16; ++i){ int j = p + 16*i; acc = fd2(shh[j], wr[j], acc); }
                pp[rr][p] = acc;
            }
            __syncthreads();
            if (tid < 30){
                float pv = winb[tid];
                #pragma unroll
                for (int i = 0; i < 16; ++i) pv += pp[tid][i];
                float e = expf(pv);
                if (tid < KA_) sa[tid] = e;
                else if (tid < 2*KA_) sbv[tid-KA_] = e;
                else {
                    int a2 = tid - 2*KA_;
                    float kn = ((t == 0) ? 0.f : skst[a2]) + e;
                    skst[a2] = kn; sk[a2] = kn;
                }
            }
            __syncthreads();
            if (tid < U_){
                float acc = 0.f;
                #pragma unroll
                for (int a = 0; a < KA_; ++a){
                    float d = sk[a] - (float)tid;
                    acc += sa[a]*expf(-sbv[a]*d*d);
                }
                sphi[tid] = acc * smask[tid]*smask[tid];
            }
            __syncthreads();
            if (tid < V_){
                float wv = 0.f;
                for (int u = 0; u < U_; ++u) wv += (sseq[u] == tid) ? sphi[u] : 0.f;
                satt[tid] = wv;
            }
            __syncthreads();
            if (tid < 40){
                coh_store_u32(attnb + (size_t)t*2560 + (size_t)wb*40 + tid,
                              pkh(satt[2*tid], satt[2*tid+1]));
                asm volatile("s_waitcnt vmcnt(0)" ::: "memory");
                if (tid == 0) coh_store_u32(cfw + (size_t)t*1024 + wb*FSTRIDE, 1u);
            }
        }
        return;
    }

    // ---------------- layer role ----------------
    const int l   = bid >> 6;
    const int blk = bid & 63;
    const int ub  = blk * 8;
    const int cu  = ub + r;

    const unsigned* wsrc; int RW;
    const float* bias_p; unsigned* hbo; const unsigned* hbp;
    unsigned* cfself; const unsigned* cfprev;
    if (l == 0){ wsrc = wpad32;          RW = RW0;  bias_p = b0; hbo = out0b; hbp = nullptr; cfself = cf0; cfprev = nullptr; }
    else if (l == 1){ wsrc = wpad32 + WOFF1; RW = RW12; bias_p = b1; hbo = out1b; hbp = out0b; cfself = cf1; cfprev = cf0; }
    else { wsrc = wpad32 + WOFF2; RW = RW12; bias_p = b2; hbo = out2b; hbp = out1b; cfself = cf2; cfprev = cf1; }

    unsigned* wl = dynls;                       // 32*RW u32
    float* shf = (float*)(dynls + 32*RW);       // 512 f32 transpose buffer
    for (int i = tid; i < 32*RW; i += 512){
        int row = i / RW, j = i - row*RW;
        int ul = row >> 2, g = row & 3;
        wl[i] = wsrc[(size_t)(g*H_ + ub + ul)*RW + j];
    }
    __syncthreads();

    const uint4* Wr0 = (const uint4*)(wl + (size_t)(r*4+0)*RW);
    const uint4* Wr1 = (const uint4*)(wl + (size_t)(r*4+1)*RW);
    const uint4* Wr2 = (const uint4*)(wl + (size_t)(r*4+2)*RW);
    const uint4* Wr3 = (const uint4*)(wl + (size_t)(r*4+3)*RW);

    // stroke weights (f16 elems 0..2 of each gate row) -> registers
    float stw[4][3];
    #pragma unroll
    for (int g = 0; g < 4; ++g){
        unsigned wa = wl[(size_t)(r*4+g)*RW + 0];
        unsigned wb2 = wl[(size_t)(r*4+g)*RW + 1];
        stw[g][0] = hlo(wa); stw[g][1] = hhi(wa); stw[g][2] = hlo(wb2);
    }
    const float bq0 = bias_p[0*H_+cu];
    const float bq1 = bias_p[1*H_+cu];
    const float bq2 = bias_p[2*H_+cu];
    const float bq3 = bias_p[3*H_+cu];
    float creg = 0.f;

    for (int t = 0; t < T_; ++t){
        const float* sr = strokes + ((size_t)b*T_ + t)*3;
        float sx = sr[0], sy = sr[1], sz = sr[2];
        float a0 = sx*stw[0][0] + sy*stw[0][1] + sz*stw[0][2];
        float a1 = sx*stw[1][0] + sy*stw[1][1] + sz*stw[1][2];
        float a2 = sx*stw[2][0] + sy*stw[2][1] + sz*stw[2][2];
        float a3 = sx*stw[3][0] + sy*stw[3][1] + sz*stw[3][2];

        if (l == 0){
            if (t > 0){
                wait_role(cf0 + (size_t)(t-1)*1024);
                const uint4* hq = (const uint4*)hbo + (size_t)(t-1)*4096 + b;
                #pragma unroll 4
                for (int kp = 0; kp < 64; ++kp){
                    uint4 q = hq[(size_t)kp*64];
                    a0 = dot8(q, Wr0[11+kp], a0);
                    a1 = dot8(q, Wr1[11+kp], a1);
                    a2 = dot8(q, Wr2[11+kp], a2);
                    a3 = dot8(q, Wr3[11+kp], a3);
                }
                wait_role(cfw + (size_t)(t-1)*1024);
                const uint4* ap = (const uint4*)(attnb + (size_t)(t-1)*2560 + (size_t)b*40);
                #pragma unroll
                for (int j = 0; j < 10; ++j){
                    uint4 q = ap[j];
                    a0 = dot8(q, Wr0[1+j], a0);
                    a1 = dot8(q, Wr1[1+j], a1);
                    a2 = dot8(q, Wr2[1+j], a2);
                    a3 = dot8(q, Wr3[1+j], a3);
                }
            }
        } else {
            // parallel triple-wait: wave0 -> own(t-1), wave1 -> prev(t), wave2 -> window(t)
            if (tid < 64){
                if (t > 0){
                    const unsigned* p = cfself + (size_t)(t-1)*1024 + tid*FSTRIDE;
                    while (coh_load_u32(p) == 0){}
                }
            } else if (tid < 128){
                const unsigned* p = cfprev + (size_t)t*1024 + (tid-64)*FSTRIDE;
                while (coh_load_u32(p) == 0){}
            } else if (tid < 192){
                const unsigned* p = cfw + (size_t)t*1024 + (tid-128)*FSTRIDE;
                while (coh_load_u32(p) == 0){}
            }
            __syncthreads();
            const uint4* hc = (const uint4*)hbp + (size_t)t*4096 + b;
            if (t > 0){
                const uint4* ho = (const uint4*)hbo + (size_t)(t-1)*4096 + b;
                #pragma unroll 2
                for (int kp = 0; kp < 64; ++kp){
                    uint4 qo = ho[(size_t)kp*64];
                    uint4 qc = hc[(size_t)kp*64];
                    a0 = dot8(qo, Wr0[75+kp], a0); a0 = dot8(qc, Wr0[11+kp], a0);
                    a1 = dot8(qo, Wr1[75+kp], a1); a1 = dot8(qc, Wr1[11+kp], a1);
                    a2 = dot8(qo, Wr2[75+kp], a2); a2 = dot8(qc, Wr2[11+kp], a2);
                    a3 = dot8(qo, Wr3[75+kp], a3); a3 = dot8(qc, Wr3[11+kp], a3);
                }
            } else {
                #pragma unroll 4
                for (int kp = 0; kp < 64; ++kp){
                    uint4 qc = hc[(size_t)kp*64];
                    a0 = dot8(qc, Wr0[11+kp], a0);
                    a1 = dot8(qc, Wr1[11+kp], a1);
                    a2 = dot8(qc, Wr2[11+kp], a2);
                    a3 = dot8(qc, Wr3[11+kp], a3);
                }
            }
            const uint4* ap = (const uint4*)(attnb + (size_t)t*2560 + (size_t)b*40);
            #pragma unroll
            for (int j = 0; j < 10; ++j){
                uint4 q = ap[j];
                a0 = dot8(q, Wr0[1+j], a0);
                a1 = dot8(q, Wr1[1+j], a1);
                a2 = dot8(q, Wr2[1+j], a2);
                a3 = dot8(q, Wr3[1+j], a3);
            }
        }

        // combine: thread (r,b) owns unit cu
        {
            float gi  = a0 + bq0;
            float gf  = a1 + bq1;
            float gg_ = a2 + bq2;
            float go  = a3 + bq3;
            float cold = (t == 0) ? 0.f : creg;
            float cnew = sigmf(gf)*cold + sigmf(gi)*tanhf(gg_);
            creg = cnew;
            shf[r*64 + b] = sigmf(go)*tanhf(cnew);
        }
        __syncthreads();
        if (tid < 64){
            u32x4 v;
            v.x = pkh(shf[0*64+tid], shf[1*64+tid]);
            v.y = pkh(shf[2*64+tid], shf[3*64+tid]);
            v.z = pkh(shf[4*64+tid], shf[5*64+tid]);
            v.w = pkh(shf[6*64+tid], shf[7*64+tid]);
            coh_store_u128(hbo + (size_t)t*16384 + (size_t)blk*256 + tid*4, v);
            asm volatile("s_waitcnt vmcnt(0)" ::: "memory");
            if (tid == 0) coh_store_u32(cfself + (size_t)t*1024 + blk*FSTRIDE, 1u);
        }
    }
}

// ---------------------------------------------------------------------------
// FC head + output transforms. One block per t; h inputs are f16 pairs.
__global__ __launch_bounds__(256) void k_fc(
    const unsigned* __restrict__ out0b, const unsigned* __restrict__ out1b, const unsigned* __restrict__ out2b,
    const float* __restrict__ fcW, const float* __restrict__ fcb, float* __restrict__ out)
{
    int t = blockIdx.x; int tid = threadIdx.x;
    int b = tid & 63; int gq = tid >> 6;
    __shared__ float smraw[128*65];

    float acc[31];
    #pragma unroll
    for (int i = 0; i < 31; ++i) acc[i] = 0.f;

    const unsigned* hbs[3] = {out0b, out1b, out2b};
    for (int seg = 0; seg < 3; ++seg){
        const uint4* o = (const uint4*)hbs[seg];
        for (int kc = 0; kc < H_; kc += 128){
            int kp0 = kc >> 3;
            __syncthreads();
            #pragma unroll
            for (int rr = 0; rr < 4; ++rr){
                int idx = tid + 256*rr;
                int kq  = idx >> 6;
                int bb  = idx & 63;
                uint4 v = o[((size_t)t*64 + kp0 + kq)*64 + bb];
                int kb = kq*8;
                smraw[(kb+0)*65+bb]=hlo(v.x); smraw[(kb+1)*65+bb]=hhi(v.x);
                smraw[(kb+2)*65+bb]=hlo(v.y); smraw[(kb+3)*65+bb]=hhi(v.y);
                smraw[(kb+4)*65+bb]=hlo(v.z); smraw[(kb+5)*65+bb]=hhi(v.z);
                smraw[(kb+6)*65+bb]=hlo(v.w); smraw[(kb+7)*65+bb]=hhi(v.w);
            }
            __syncthreads();
            for (int kk = 0; kk < 128; kk += 4){
                float a0 = smraw[(kk+0)*65+b];
                float a1 = smraw[(kk+1)*65+b];
                float a2 = smraw[(kk+2)*65+b];
                float a3 = smraw[(kk+3)*65+b];
                int K = seg*H_ + kc + kk;
                #pragma unroll
                for (int i = 0; i < 30; ++i){
                    float4 w = *(const float4*)(fcW + (size_t)(gq+4*i)*1536 + K);
                    acc[i] += a0*w.x + a1*w.y + a2*w.z + a3*w.w;
                }
                if (gq == 0){
                    float4 w = *(const float4*)(fcW + (size_t)120*1536 + K);
                    acc[30] += a0*w.x + a1*w.y + a2*w.z + a3*w.w;
                }
            }
        }
    }
    __syncthreads();
    #pragma unroll
    for (int i = 0; i < 30; ++i) smraw[(gq+4*i)*64 + b] = acc[i] + fcb[gq+4*i];
    if (gq == 0) smraw[120*64 + b] = acc[30] + fcb[120];
    __syncthreads();

    if (tid < 64){
        size_t bt = (size_t)b*T_ + t;
        float* myu = out + 768000;
        #pragma unroll
        for (int q = 0; q < 10; ++q){
            float4 v;
            v.x = smraw[(4*q+0)*64+b]; v.y = smraw[(4*q+1)*64+b];
            v.z = smraw[(4*q+2)*64+b]; v.w = smraw[(4*q+3)*64+b];
            *(float4*)(myu + bt*40 + 4*q) = v;
        }
        float* lsg = out + 2304000;
        #pragma unroll
        for (int q = 0; q < 10; ++q){
            float4 v;
            v.x = smraw[(40+4*q+0)*64+b]; v.y = smraw[(40+4*q+1)*64+b];
            v.z = smraw[(40+4*q+2)*64+b]; v.w = smraw[(40+4*q+3)*64+b];
            *(float4*)(lsg + bt*40 + 4*q) = v;
        }
        float pi[KO_];
        float m = -1e30f;
        #pragma unroll
        for (int ko = 0; ko < KO_; ++ko){ pi[ko] = smraw[(80+ko)*64+b]; m = fmaxf(m, pi[ko]); }
        float s = 0.f;
        #pragma unroll
        for (int ko = 0; ko < KO_; ++ko) s += expf(pi[ko]-m);
        float lse = m + logf(s);
        #pragma unroll
        for (int q = 0; q < 5; ++q){
            float4 v;
            v.x = pi[4*q+0]-lse; v.y = pi[4*q+1]-lse; v.z = pi[4*q+2]-lse; v.w = pi[4*q+3]-lse;
            *(float4*)(out + bt*20 + 4*q) = v;
        }
        float* rho = out + 3840000;
        #pragma unroll
        for (int q = 0; q < 5; ++q){
            float4 v;
            v.x = tanhf(smraw[(100+4*q+0)*64+b]); v.y = tanhf(smraw[(100+4*q+1)*64+b]);
            v.z = tanhf(smraw[(100+4*q+2)*64+b]); v.w = tanhf(smraw[(100+4*q+3)*64+b]);
            *(float4*)(rho + bt*20 + 4*q) = v;
        }
        out[4608000 + bt] = 1.f/(1.f + expf(smraw[120*64+b]));
    }
}

// ---------------------------------------------------------------------------
extern "C" void kernel_launch(void* const* d_in, const int* in_sizes, int n_in,
                              void* d_out, int out_size, void* d_ws, size_t ws_size,
                              hipStream_t stream)
{
    const int*   char_seq  = (const int*)  d_in[0];
    const float* char_mask = (const float*)d_in[1];
    const float* strokes   = (const float*)d_in[2];
    const float* W0ih = (const float*)d_in[4];
    const float* W0hh = (const float*)d_in[5];
    const float* b0   = (const float*)d_in[6];
    const float* winW = (const float*)d_in[7];
    const float* winb = (const float*)d_in[8];
    const float* W1ih = (const float*)d_in[9];
    const float* W1hh = (const float*)d_in[10];
    const float* b1   = (const float*)d_in[11];
    const float* W2ih = (const float*)d_in[12];
    const float* W2hh = (const float*)d_in[13];
    const float* b2   = (const float*)d_in[14];
    const float* fcW  = (const float*)d_in[15];
    const float* fcb  = (const float*)d_in[16];

    unsigned* out0b  = (unsigned*)d_ws;            // [600][64][64] uint4 = 9,830,400 u32
    unsigned* out1b  = out0b + 9830400;
    unsigned* out2b  = out1b + 9830400;
    unsigned* attnb  = out2b + 9830400;            // [600][64][40] u32 = 1,536,000
    unsigned* wpad32 = attnb + 1536000;            // 2,899,456 u32
    unsigned* flags  = wpad32 + 2899456;           // 4 roles x 600 x 64 x 16 u32 = 2,457,600

    (void)hipMemsetAsync(flags, 0, 2457600u*sizeof(unsigned), stream);

    hipLaunchKernelGGL(k_prep, dim3(6174), dim3(64), 0, stream,
        W0ih, W0hh, W1ih, W1hh, W2ih, W2hh, winW, wpad32);

    const int dyn_bytes = (32*RW12 + 512) * 4;     // 73,216 B
    (void)hipFuncSetAttribute((const void*)k_pipe,
        hipFuncAttributeMaxDynamicSharedMemorySize, dyn_bytes);

    hipLaunchKernelGGL(k_pipe, dim3(256), dim3(512), dyn_bytes, stream,
        strokes, char_seq, char_mask, wpad32, winb, b0, b1, b2,
        out0b, out1b, out2b, attnb, flags);

    hipLaunchKernelGGL(k_fc, dim3(600), dim3(256), 0, stream,
        out0b, out1b, out2b, fcW, fcb, (float*)d_out);
}